// Round 13
// baseline (1341.372 us; speedup 1.0000x reference)
//
#include <hip/hip_runtime.h>

#define Bsz  256
#define Tlen 2048
#define Hdim 128

typedef __fp16 hf2 __attribute__((ext_vector_type(2)));

// Raw-HW transcendentals (VOP1, 1 instr each, ~1 ulp). R12-verified: broke the
// 1530-us VALU floor (precise IEEE div/exp sequences were the hidden hog).
__device__ __forceinline__ float fexp2_(float x) {
    float r; asm("v_exp_f32 %0, %1" : "=v"(r) : "v"(x)); return r;
}
__device__ __forceinline__ float frcp_(float x) {
    float r; asm("v_rcp_f32 %0, %1" : "=v"(r) : "v"(x)); return r;
}
__device__ __forceinline__ float sigmoidf_(float v) {
    return frcp_(1.0f + fexp2_(v * -1.44269504f));
}
__device__ __forceinline__ float tanhf_(float v) {
    return 1.0f - 2.0f * frcp_(fexp2_(v * 2.88539008f) + 1.0f);
}

// DPP butterfly add over groups of 8 consecutive lanes — pure VALU pipe.
template <int CTRL>
__device__ __forceinline__ float dpp_add(float v) {
    int t = __builtin_amdgcn_update_dpp(0, __float_as_int(v), CTRL, 0xf, 0xf, true);
    return v + __int_as_float(t);
}
// 0xB1 quad_perm xor1, 0x4E quad_perm xor2, 0x141 row_half_mirror.
__device__ __forceinline__ float red8(float v) {
    v = dpp_add<0xB1>(v);
    v = dpp_add<0x4E>(v);
    v = dpp_add<0x141>(v);
    return v;
}

// --- named packed-f16 weight strips (16 f32 -> 8 packed VGPRs each) ---
#define DECL8(p) hf2 p##0, p##1, p##2, p##3, p##4, p##5, p##6, p##7
#define LOAD8H(p, ptr) do {                                          \
    const float4* _q = (const float4*)(ptr);                         \
    float4 _a = _q[0], _b = _q[1], _c = _q[2], _d = _q[3];           \
    p##0 = __builtin_amdgcn_cvt_pkrtz(_a.x, _a.y);                   \
    p##1 = __builtin_amdgcn_cvt_pkrtz(_a.z, _a.w);                   \
    p##2 = __builtin_amdgcn_cvt_pkrtz(_b.x, _b.y);                   \
    p##3 = __builtin_amdgcn_cvt_pkrtz(_b.z, _b.w);                   \
    p##4 = __builtin_amdgcn_cvt_pkrtz(_c.x, _c.y);                   \
    p##5 = __builtin_amdgcn_cvt_pkrtz(_c.z, _c.w);                   \
    p##6 = __builtin_amdgcn_cvt_pkrtz(_d.x, _d.y);                   \
    p##7 = __builtin_amdgcn_cvt_pkrtz(_d.z, _d.w); } while (0)
// IN-LOOP pin: redefines the 8 values every iteration via an empty volatile
// asm. This makes the weights loop-CARRIED (not rematerializable loop-invariant
// loads), so the allocator's only alternative to register residency is a
// per-iteration spill store+reload — strictly worse. Defeats the remat churn
// that kept VGPR_Count at ~60 and duration at ~2x the hand-counted VALU work
// through R1-R12. Emits ZERO instructions.
#define PINH8(p) asm volatile("" : "+v"(p##0), "+v"(p##1), "+v"(p##2), \
    "+v"(p##3), "+v"(p##4), "+v"(p##5), "+v"(p##6), "+v"(p##7))
#define PINF7(a,b,c,d,e,f,g) asm volatile("" : "+v"(a), "+v"(b), "+v"(c), \
    "+v"(d), "+v"(e), "+v"(f), "+v"(g))
// 8 chained v_dot2_f32_f16: acc += sum_j p_j . h_j  (f32 accumulate)
#define DOT8(acc, p) do {                                            \
    acc = __builtin_amdgcn_fdot2(p##0, h0, acc, false);              \
    acc = __builtin_amdgcn_fdot2(p##1, h1, acc, false);              \
    acc = __builtin_amdgcn_fdot2(p##2, h2, acc, false);              \
    acc = __builtin_amdgcn_fdot2(p##3, h3, acc, false);              \
    acc = __builtin_amdgcn_fdot2(p##4, h4, acc, false);              \
    acc = __builtin_amdgcn_fdot2(p##5, h5, acc, false);              \
    acc = __builtin_amdgcn_fdot2(p##6, h6, acc, false);              \
    acc = __builtin_amdgcn_fdot2(p##7, h7, acc, false); } while (0)

// grid = 256 blocks (one batch row per block), block = 512 threads (8 waves).
// thread t: kc = t & 7 -> k-chunk [kc*16, kc*16+16)
//           rg = t >> 3 -> unit pair u0 = 2*rg, u0+1; owns Whh rows
//           {u0,u0+1} x {r,z,n} over its k-chunk as packed f16 (56 VGPRs of
//           weights, held live by in-loop pins; budget 256 via launch_bounds).
// h lives in LDS as packed f16, chunk kc at hf2 index kc*12 (48B stride:
// 16B-aligned, banks kc*12%32 = {0,12,24,4,16,28,8,20} all distinct).
__global__ __launch_bounds__(512, 2)
void rnn_imp_kernel(const float* __restrict__ x,     // [B, T] (I=1)
                    const float* __restrict__ Wih,   // [384]
                    const float* __restrict__ Whh,   // [384, 128]
                    const float* __restrict__ bih,   // [384]
                    const float* __restrict__ bhh,   // [384]
                    const float* __restrict__ Wfc,   // [128]
                    const float* __restrict__ bfc,   // [1]
                    float* __restrict__ out_newin,   // [T, B]
                    float* __restrict__ out_pred)    // [B, T-1]
{
    __shared__ __align__(16) float x_s[Tlen + 4];
    __shared__ __align__(16) hf2  h16_s[2][96];      // 8 chunks x (8 data + 4 pad)

    const int tid = threadIdx.x;
    const int b   = blockIdx.x;
    const int kc  = tid & 7;
    const int rg  = tid >> 3;
    const int u0  = rg * 2;

    // stage x row (coalesced) and zero h buffer 0
    for (int i = tid; i < Tlen; i += 512) x_s[i] = x[b * Tlen + i];
    if (tid < 96) h16_s[0][tid] = hf2{(__fp16)0, (__fp16)0};

    // weight strips -> packed f16 named scalars
    DECL8(wr0); DECL8(wr1); DECL8(wz0); DECL8(wz1); DECL8(wn0); DECL8(wn1); DECL8(wf);
    LOAD8H(wr0, Whh + (0 * Hdim + u0 + 0) * Hdim + kc * 16);
    LOAD8H(wr1, Whh + (0 * Hdim + u0 + 1) * Hdim + kc * 16);
    LOAD8H(wz0, Whh + (1 * Hdim + u0 + 0) * Hdim + kc * 16);
    LOAD8H(wz1, Whh + (1 * Hdim + u0 + 1) * Hdim + kc * 16);
    LOAD8H(wn0, Whh + (2 * Hdim + u0 + 0) * Hdim + kc * 16);
    LOAD8H(wn1, Whh + (2 * Hdim + u0 + 1) * Hdim + kc * 16);
    LOAD8H(wf,  Wfc + kc * 16);

    // per-unit gate constants (identical across the 8 lanes of a group).
    // NON-const: they are pinned in-loop to stop per-step re-loads.
    float wih_r0 = Wih[u0],     wih_r1 = Wih[u0 + 1];
    float wih_z0 = Wih[u0+128], wih_z1 = Wih[u0 + 129];
    float wih_n0 = Wih[u0+256], wih_n1 = Wih[u0 + 257];
    float bb_r0 = bih[u0]     + bhh[u0],       bb_r1 = bih[u0+1]   + bhh[u0+1];
    float bb_z0 = bih[u0+128] + bhh[u0+128],   bb_z1 = bih[u0+129] + bhh[u0+129];
    float bi_n0 = bih[u0+256], bi_n1 = bih[u0 + 257];
    float bh_n0 = bhh[u0+256], bh_n1 = bhh[u0 + 257];
    const float bfc0 = bfc[0];                 // wave-uniform -> SGPR, cheap
    float h_old0 = 0.0f, h_old1 = 0.0f;

    const int rbase = kc * 12;                              // hf2 chunk base
    const int pw    = (u0 >> 4) * 12 + ((u0 >> 1) & 7);     // hf2 write slot

    __syncthreads();

#pragma unroll 1
    for (int t = 0; t < Tlen; ++t) {
        // ---- loop-carry pins: weights + gate consts become loop-variant ----
        PINH8(wr0); PINH8(wr1); PINH8(wz0); PINH8(wz1);
        PINH8(wn0); PINH8(wn1); PINH8(wf);
        PINF7(wih_r0, wih_z0, wih_n0, bb_r0, bb_z0, bi_n0, bh_n0);
        PINF7(wih_r1, wih_z1, wih_n1, bb_r1, bb_z1, bi_n1, bh_n1);

        const hf2* hb = h16_s[t & 1];
        hf2*       hw = h16_s[(t + 1) & 1];
        float xt = x_s[t];

        // h chunk: 2x ds_read_b128 of packed f16 (16 values)
        const float4* hp = (const float4*)(hb + rbase);
        float4 qa = hp[0], qb = hp[1];
        hf2 h0 = __builtin_bit_cast(hf2, qa.x), h1 = __builtin_bit_cast(hf2, qa.y),
            h2 = __builtin_bit_cast(hf2, qa.z), h3 = __builtin_bit_cast(hf2, qa.w),
            h4 = __builtin_bit_cast(hf2, qb.x), h5 = __builtin_bit_cast(hf2, qb.y),
            h6 = __builtin_bit_cast(hf2, qb.z), h7 = __builtin_bit_cast(hf2, qb.w);

        float ar0 = 0.f, ar1 = 0.f, az0 = 0.f, az1 = 0.f,
              an0 = 0.f, an1 = 0.f, axp = 0.f;
        DOT8(axp, wf);                  // xp first: xh feeds the gate chain
        DOT8(ar0, wr0); DOT8(ar1, wr1);
        DOT8(az0, wz0); DOT8(az1, wz1);
        DOT8(an0, wn0); DOT8(an1, wn1);

        // 8-lane DPP butterfly; every lane ends with the full sums
        float xp  = red8(axp);
        float gr0 = red8(ar0);
        float gr1 = red8(ar1);
        float gz0 = red8(az0);
        float gz1 = red8(az1);
        float gn0 = red8(an0);
        float gn1 = red8(an1);

        float xh  = xp + bfc0;
        float cur = ((xt == 128.0f) && (t != 0)) ? xh : xt;

        float r0 = sigmoidf_(wih_r0 * cur + bb_r0 + gr0);
        float z0 = sigmoidf_(wih_z0 * cur + bb_z0 + gz0);
        float n0 = tanhf_(wih_n0 * cur + bi_n0 + r0 * (gn0 + bh_n0));
        float hn0 = (1.0f - z0) * n0 + z0 * h_old0;

        float r1 = sigmoidf_(wih_r1 * cur + bb_r1 + gr1);
        float z1 = sigmoidf_(wih_z1 * cur + bb_z1 + gz1);
        float n1 = tanhf_(wih_n1 * cur + bi_n1 + r1 * (gn1 + bh_n1));
        float hn1 = (1.0f - z1) * n1 + z1 * h_old1;

        h_old0 = hn0; h_old1 = hn1;

        if (kc == 0) {
            hw[pw] = __builtin_amdgcn_cvt_pkrtz(hn0, hn1);
        }
        if (tid == 0) {
            out_newin[t * Bsz + b] = cur;
            if (t != 0) out_pred[b * (Tlen - 1) + (t - 1)] = xh;
        }
        __syncthreads();
    }
}

extern "C" void kernel_launch(void* const* d_in, const int* in_sizes, int n_in,
                              void* d_out, int out_size, void* d_ws, size_t ws_size,
                              hipStream_t stream) {
    const float* x   = (const float*)d_in[0];
    const float* Wih = (const float*)d_in[1];
    const float* Whh = (const float*)d_in[2];
    const float* bih = (const float*)d_in[3];
    const float* bhh = (const float*)d_in[4];
    const float* Wfc = (const float*)d_in[5];
    const float* bfc = (const float*)d_in[6];

    float* out_newin = (float*)d_out;                 // [T*B] = 524288
    float* out_pred  = out_newin + Tlen * Bsz;        // [B*(T-1)] = 524032

    rnn_imp_kernel<<<Bsz, 512, 0, stream>>>(x, Wih, Whh, bih, bhh, Wfc, bfc,
                                            out_newin, out_pred);
}

// Round 14
// 1308.795 us; speedup vs baseline: 1.0249x; 1.0249x over previous
//
#include <hip/hip_runtime.h>

#define Bsz  256
#define Tlen 2048
#define Hdim 128

typedef __fp16 hf2 __attribute__((ext_vector_type(2)));

// Raw-HW transcendentals (VOP1, 1 instr each, ~1 ulp). R12-verified: broke the
// 1530-us VALU floor (precise IEEE div/exp sequences were the hidden hog).
__device__ __forceinline__ float fexp2_(float x) {
    float r; asm("v_exp_f32 %0, %1" : "=v"(r) : "v"(x)); return r;
}
__device__ __forceinline__ float frcp_(float x) {
    float r; asm("v_rcp_f32 %0, %1" : "=v"(r) : "v"(x)); return r;
}
__device__ __forceinline__ float sigmoidf_(float v) {
    return frcp_(1.0f + fexp2_(v * -1.44269504f));
}
__device__ __forceinline__ float tanhf_(float v) {
    return 1.0f - 2.0f * frcp_(fexp2_(v * 2.88539008f) + 1.0f);
}

// DPP butterfly add over groups of 8 consecutive lanes — pure VALU pipe.
template <int CTRL>
__device__ __forceinline__ float dpp_add(float v) {
    int t = __builtin_amdgcn_update_dpp(0, __float_as_int(v), CTRL, 0xf, 0xf, true);
    return v + __int_as_float(t);
}
// 0xB1 quad_perm xor1, 0x4E quad_perm xor2, 0x141 row_half_mirror.
__device__ __forceinline__ float red8(float v) {
    v = dpp_add<0xB1>(v);
    v = dpp_add<0x4E>(v);
    v = dpp_add<0x141>(v);
    return v;
}

// --- named packed-f16 weight strips (16 f32 -> 8 packed VGPRs each) ---
#define DECL8(p) hf2 p##0, p##1, p##2, p##3, p##4, p##5, p##6, p##7
#define LOAD8H(p, ptr) do {                                          \
    const float4* _q = (const float4*)(ptr);                         \
    float4 _a = _q[0], _b = _q[1], _c = _q[2], _d = _q[3];           \
    p##0 = __builtin_amdgcn_cvt_pkrtz(_a.x, _a.y);                   \
    p##1 = __builtin_amdgcn_cvt_pkrtz(_a.z, _a.w);                   \
    p##2 = __builtin_amdgcn_cvt_pkrtz(_b.x, _b.y);                   \
    p##3 = __builtin_amdgcn_cvt_pkrtz(_b.z, _b.w);                   \
    p##4 = __builtin_amdgcn_cvt_pkrtz(_c.x, _c.y);                   \
    p##5 = __builtin_amdgcn_cvt_pkrtz(_c.z, _c.w);                   \
    p##6 = __builtin_amdgcn_cvt_pkrtz(_d.x, _d.y);                   \
    p##7 = __builtin_amdgcn_cvt_pkrtz(_d.z, _d.w); } while (0)
#define PINH8(p) asm volatile("" : "+v"(p##0), "+v"(p##1), "+v"(p##2), \
    "+v"(p##3), "+v"(p##4), "+v"(p##5), "+v"(p##6), "+v"(p##7))
#define PINF7(a,b,c,d,e,f,g) asm volatile("" : "+v"(a), "+v"(b), "+v"(c), \
    "+v"(d), "+v"(e), "+v"(f), "+v"(g))
// 8 chained v_dot2_f32_f16: acc += sum_j p_j . h_j  (f32 accumulate)
#define DOT8(acc, p) do {                                            \
    acc = __builtin_amdgcn_fdot2(p##0, h0, acc, false);              \
    acc = __builtin_amdgcn_fdot2(p##1, h1, acc, false);              \
    acc = __builtin_amdgcn_fdot2(p##2, h2, acc, false);              \
    acc = __builtin_amdgcn_fdot2(p##3, h3, acc, false);              \
    acc = __builtin_amdgcn_fdot2(p##4, h4, acc, false);              \
    acc = __builtin_amdgcn_fdot2(p##5, h5, acc, false);              \
    acc = __builtin_amdgcn_fdot2(p##6, h6, acc, false);              \
    acc = __builtin_amdgcn_fdot2(p##7, h7, acc, false); } while (0)

// grid = 256 blocks (one batch row per block), block = 512 threads (8 waves).
// thread t: kc = t & 7 -> k-chunk [kc*16, kc*16+16)
//           rg = t >> 3 -> unit pair u0 = 2*rg, u0+1 as packed f16.
// R14 change: ZERO global stores inside the t-loop. Outputs staged in LDS
// (cur -> x_s[t] in place, xh -> xh_s[t]) and bulk-flushed after the loop.
// Rationale: compiler emits s_waitcnt vmcnt(0) before every s_barrier; wave 0's
// 2 in-loop global stores made all 8 waves wait ~150-300 cyc of store-ack
// latency at EVERY step's barrier. (In-step LDS overwrite of x_s[t] is
// race-safe: every thread computes identical cur/xh, so pre- vs post-write
// reads yield the same value.)
__global__ __launch_bounds__(512, 2)
void rnn_imp_kernel(const float* __restrict__ x,     // [B, T] (I=1)
                    const float* __restrict__ Wih,   // [384]
                    const float* __restrict__ Whh,   // [384, 128]
                    const float* __restrict__ bih,   // [384]
                    const float* __restrict__ bhh,   // [384]
                    const float* __restrict__ Wfc,   // [128]
                    const float* __restrict__ bfc,   // [1]
                    float* __restrict__ out_newin,   // [T, B]
                    float* __restrict__ out_pred)    // [B, T-1]
{
    __shared__ __align__(16) float x_s[Tlen + 4];
    __shared__ __align__(16) float xh_s[Tlen + 4];
    __shared__ __align__(16) hf2  h16_s[2][96];      // 8 chunks x (8 data + 4 pad)

    const int tid = threadIdx.x;
    const int b   = blockIdx.x;
    const int kc  = tid & 7;
    const int rg  = tid >> 3;
    const int u0  = rg * 2;

    // stage x row (coalesced) and zero h buffer 0
    for (int i = tid; i < Tlen; i += 512) x_s[i] = x[b * Tlen + i];
    if (tid < 96) h16_s[0][tid] = hf2{(__fp16)0, (__fp16)0};

    // weight strips -> packed f16 named scalars
    DECL8(wr0); DECL8(wr1); DECL8(wz0); DECL8(wz1); DECL8(wn0); DECL8(wn1); DECL8(wf);
    LOAD8H(wr0, Whh + (0 * Hdim + u0 + 0) * Hdim + kc * 16);
    LOAD8H(wr1, Whh + (0 * Hdim + u0 + 1) * Hdim + kc * 16);
    LOAD8H(wz0, Whh + (1 * Hdim + u0 + 0) * Hdim + kc * 16);
    LOAD8H(wz1, Whh + (1 * Hdim + u0 + 1) * Hdim + kc * 16);
    LOAD8H(wn0, Whh + (2 * Hdim + u0 + 0) * Hdim + kc * 16);
    LOAD8H(wn1, Whh + (2 * Hdim + u0 + 1) * Hdim + kc * 16);
    LOAD8H(wf,  Wfc + kc * 16);

    // per-unit gate constants (identical across the 8 lanes of a group)
    float wih_r0 = Wih[u0],     wih_r1 = Wih[u0 + 1];
    float wih_z0 = Wih[u0+128], wih_z1 = Wih[u0 + 129];
    float wih_n0 = Wih[u0+256], wih_n1 = Wih[u0 + 257];
    float bb_r0 = bih[u0]     + bhh[u0],       bb_r1 = bih[u0+1]   + bhh[u0+1];
    float bb_z0 = bih[u0+128] + bhh[u0+128],   bb_z1 = bih[u0+129] + bhh[u0+129];
    float bi_n0 = bih[u0+256], bi_n1 = bih[u0 + 257];
    float bh_n0 = bhh[u0+256], bh_n1 = bhh[u0 + 257];
    const float bfc0 = bfc[0];
    float h_old0 = 0.0f, h_old1 = 0.0f;

    const int rbase = kc * 12;                              // hf2 chunk base
    const int pw    = (u0 >> 4) * 12 + ((u0 >> 1) & 7);     // hf2 write slot

    __syncthreads();

#pragma unroll 1
    for (int t = 0; t < Tlen; ++t) {
        // loop-carry pins (R13: neutral; kept constant to isolate this round's
        // single variable — the removal of in-loop global stores)
        PINH8(wr0); PINH8(wr1); PINH8(wz0); PINH8(wz1);
        PINH8(wn0); PINH8(wn1); PINH8(wf);
        PINF7(wih_r0, wih_z0, wih_n0, bb_r0, bb_z0, bi_n0, bh_n0);
        PINF7(wih_r1, wih_z1, wih_n1, bb_r1, bb_z1, bi_n1, bh_n1);

        const hf2* hb = h16_s[t & 1];
        hf2*       hw = h16_s[(t + 1) & 1];
        float xt = x_s[t];

        // h chunk: 2x ds_read_b128 of packed f16 (16 values)
        const float4* hp = (const float4*)(hb + rbase);
        float4 qa = hp[0], qb = hp[1];
        hf2 h0 = __builtin_bit_cast(hf2, qa.x), h1 = __builtin_bit_cast(hf2, qa.y),
            h2 = __builtin_bit_cast(hf2, qa.z), h3 = __builtin_bit_cast(hf2, qa.w),
            h4 = __builtin_bit_cast(hf2, qb.x), h5 = __builtin_bit_cast(hf2, qb.y),
            h6 = __builtin_bit_cast(hf2, qb.z), h7 = __builtin_bit_cast(hf2, qb.w);

        float ar0 = 0.f, ar1 = 0.f, az0 = 0.f, az1 = 0.f,
              an0 = 0.f, an1 = 0.f, axp = 0.f;
        DOT8(axp, wf);                  // xp first: xh feeds the gate chain
        DOT8(ar0, wr0); DOT8(ar1, wr1);
        DOT8(az0, wz0); DOT8(az1, wz1);
        DOT8(an0, wn0); DOT8(an1, wn1);

        // 8-lane DPP butterfly; every lane ends with the full sums
        float xp  = red8(axp);
        float gr0 = red8(ar0);
        float gr1 = red8(ar1);
        float gz0 = red8(az0);
        float gz1 = red8(az1);
        float gn0 = red8(an0);
        float gn1 = red8(an1);

        float xh  = xp + bfc0;
        float cur = ((xt == 128.0f) && (t != 0)) ? xh : xt;

        float r0 = sigmoidf_(wih_r0 * cur + bb_r0 + gr0);
        float z0 = sigmoidf_(wih_z0 * cur + bb_z0 + gz0);
        float n0 = tanhf_(wih_n0 * cur + bi_n0 + r0 * (gn0 + bh_n0));
        float hn0 = (1.0f - z0) * n0 + z0 * h_old0;

        float r1 = sigmoidf_(wih_r1 * cur + bb_r1 + gr1);
        float z1 = sigmoidf_(wih_z1 * cur + bb_z1 + gz1);
        float n1 = tanhf_(wih_n1 * cur + bi_n1 + r1 * (gn1 + bh_n1));
        float hn1 = (1.0f - z1) * n1 + z1 * h_old1;

        h_old0 = hn0; h_old1 = hn1;

        if (kc == 0) {
            hw[pw] = __builtin_amdgcn_cvt_pkrtz(hn0, hn1);
        }
        if (tid == 0) {
            x_s[t]  = cur;   // LDS staging (race-safe: all threads agree)
            xh_s[t] = xh;
        }
        __syncthreads();
    }

    // bulk flush: one vmcnt drain total instead of one per step
    for (int i = tid; i < Tlen; i += 512)
        out_newin[i * Bsz + b] = x_s[i];
    for (int i = tid; i < Tlen - 1; i += 512)
        out_pred[b * (Tlen - 1) + i] = xh_s[i + 1];
}

extern "C" void kernel_launch(void* const* d_in, const int* in_sizes, int n_in,
                              void* d_out, int out_size, void* d_ws, size_t ws_size,
                              hipStream_t stream) {
    const float* x   = (const float*)d_in[0];
    const float* Wih = (const float*)d_in[1];
    const float* Whh = (const float*)d_in[2];
    const float* bih = (const float*)d_in[3];
    const float* bhh = (const float*)d_in[4];
    const float* Wfc = (const float*)d_in[5];
    const float* bfc = (const float*)d_in[6];

    float* out_newin = (float*)d_out;                 // [T*B] = 524288
    float* out_pred  = out_newin + Tlen * Bsz;        // [B*(T-1)] = 524032

    rnn_imp_kernel<<<Bsz, 512, 0, stream>>>(x, Wih, Whh, bih, bhh, Wfc, bfc,
                                            out_newin, out_pred);
}

// Round 15
// 1157.693 us; speedup vs baseline: 1.1587x; 1.1305x over previous
//
#include <hip/hip_runtime.h>

#define Bsz  256
#define Tlen 2048
#define Hdim 128

typedef __fp16 hf2 __attribute__((ext_vector_type(2)));

// Raw-HW transcendentals (VOP1, quarter-rate, ~1 ulp). R12-verified win.
__device__ __forceinline__ float fexp2_(float x) {
    float r; asm("v_exp_f32 %0, %1" : "=v"(r) : "v"(x)); return r;
}
__device__ __forceinline__ float frcp_(float x) {
    float r; asm("v_rcp_f32 %0, %1" : "=v"(r) : "v"(x)); return r;
}
__device__ __forceinline__ float sigmoidf_(float v) {
    return frcp_(1.0f + fexp2_(v * -1.44269504f));
}
__device__ __forceinline__ float tanhf_(float v) {
    return 1.0f - 2.0f * frcp_(fexp2_(v * 2.88539008f) + 1.0f);
}

// DPP butterfly add — pure VALU pipe.
template <int CTRL>
__device__ __forceinline__ float dpp_add(float v) {
    int t = __builtin_amdgcn_update_dpp(0, __float_as_int(v), CTRL, 0xf, 0xf, true);
    return v + __int_as_float(t);
}
// 4-lane allreduce within a quad (groups are quad-aligned: u = tid>>2).
// R15: 2 levels instead of 3 — half the reduce cost of the 8-lane design.
__device__ __forceinline__ float red4(float v) {
    v = dpp_add<0xB1>(v);   // quad_perm xor1
    v = dpp_add<0x4E>(v);   // quad_perm xor2
    return v;
}

__device__ __forceinline__ hf2 bch(float f) { return __builtin_bit_cast(hf2, f); }

// --- named packed-f16 weight strips (16 f32 -> 8 packed VGPRs each) ---
#define DECL8(p) hf2 p##0, p##1, p##2, p##3, p##4, p##5, p##6, p##7
#define LOAD8H(p, ptr) do {                                          \
    const float4* _q = (const float4*)(ptr);                         \
    float4 _a = _q[0], _b = _q[1], _c = _q[2], _d = _q[3];           \
    p##0 = __builtin_amdgcn_cvt_pkrtz(_a.x, _a.y);                   \
    p##1 = __builtin_amdgcn_cvt_pkrtz(_a.z, _a.w);                   \
    p##2 = __builtin_amdgcn_cvt_pkrtz(_b.x, _b.y);                   \
    p##3 = __builtin_amdgcn_cvt_pkrtz(_b.z, _b.w);                   \
    p##4 = __builtin_amdgcn_cvt_pkrtz(_c.x, _c.y);                   \
    p##5 = __builtin_amdgcn_cvt_pkrtz(_c.z, _c.w);                   \
    p##6 = __builtin_amdgcn_cvt_pkrtz(_d.x, _d.y);                   \
    p##7 = __builtin_amdgcn_cvt_pkrtz(_d.z, _d.w); } while (0)
// chained v_dot2_f32_f16 against h0..h7 / h8..h15
#define DOT8L(acc, p) do {                                           \
    acc = __builtin_amdgcn_fdot2(p##0, h0, acc, false);              \
    acc = __builtin_amdgcn_fdot2(p##1, h1, acc, false);              \
    acc = __builtin_amdgcn_fdot2(p##2, h2, acc, false);              \
    acc = __builtin_amdgcn_fdot2(p##3, h3, acc, false);              \
    acc = __builtin_amdgcn_fdot2(p##4, h4, acc, false);              \
    acc = __builtin_amdgcn_fdot2(p##5, h5, acc, false);              \
    acc = __builtin_amdgcn_fdot2(p##6, h6, acc, false);              \
    acc = __builtin_amdgcn_fdot2(p##7, h7, acc, false); } while (0)
#define DOT8H(acc, p) do {                                           \
    acc = __builtin_amdgcn_fdot2(p##0, h8,  acc, false);             \
    acc = __builtin_amdgcn_fdot2(p##1, h9,  acc, false);             \
    acc = __builtin_amdgcn_fdot2(p##2, h10, acc, false);             \
    acc = __builtin_amdgcn_fdot2(p##3, h11, acc, false);             \
    acc = __builtin_amdgcn_fdot2(p##4, h12, acc, false);             \
    acc = __builtin_amdgcn_fdot2(p##5, h13, acc, false);             \
    acc = __builtin_amdgcn_fdot2(p##6, h14, acc, false);             \
    acc = __builtin_amdgcn_fdot2(p##7, h15, acc, false); } while (0)

// grid = 256 blocks (one batch row per block), block = 512 threads (8 waves).
// R15 mapping: kc = tid & 3 (k-chunk of 32 values), u = tid >> 2 (one unit
// per 4-lane quad). Halves per-thread transcendentals (6 vs 12), gate ALU,
// and reduce depth (red4 vs red8) vs the 8-lane-group design; dot2 rises
// 56->64/thread. Net issue ~560 cyc/SIMD/step vs ~840 before.
// h in LDS as raw f16: unit u at index u + (u>>5)*8 (16B pad per 32-unit
// chunk -> lane bases 0/80/160/240 B = banks 0,20,8,28, conflict-free).
__global__ __launch_bounds__(512, 2)
void rnn_imp_kernel(const float* __restrict__ x,     // [B, T] (I=1)
                    const float* __restrict__ Wih,   // [384]
                    const float* __restrict__ Whh,   // [384, 128]
                    const float* __restrict__ bih,   // [384]
                    const float* __restrict__ bhh,   // [384]
                    const float* __restrict__ Wfc,   // [128]
                    const float* __restrict__ bfc,   // [1]
                    float* __restrict__ out_newin,   // [T, B]
                    float* __restrict__ out_pred)    // [B, T-1]
{
    __shared__ __align__(16) float  x_s[Tlen + 4];
    __shared__ __align__(16) float  xh_s[Tlen + 4];
    __shared__ __align__(16) __fp16 hbuf[2][160];   // 4 chunks x (64 data + 16B pad)

    const int tid = threadIdx.x;
    const int b   = blockIdx.x;
    const int kc  = tid & 3;
    const int u   = tid >> 2;

    // stage x row (coalesced) and zero h buffer 0
    for (int i = tid; i < Tlen; i += 512) x_s[i] = x[b * Tlen + i];
    if (tid < 160) hbuf[0][tid] = (__fp16)0.0f;

    // weight strips: rows {u, u+128, u+256} + Wfc over k in [kc*32, kc*32+32)
    DECL8(rl); DECL8(rh); DECL8(zl); DECL8(zh);
    DECL8(nl); DECL8(nh); DECL8(fl); DECL8(fh);
    const int kb = kc * 32;
    LOAD8H(rl, Whh + (0 * Hdim + u) * Hdim + kb);
    LOAD8H(rh, Whh + (0 * Hdim + u) * Hdim + kb + 16);
    LOAD8H(zl, Whh + (1 * Hdim + u) * Hdim + kb);
    LOAD8H(zh, Whh + (1 * Hdim + u) * Hdim + kb + 16);
    LOAD8H(nl, Whh + (2 * Hdim + u) * Hdim + kb);
    LOAD8H(nh, Whh + (2 * Hdim + u) * Hdim + kb + 16);
    LOAD8H(fl, Wfc + kb);
    LOAD8H(fh, Wfc + kb + 16);

    // per-unit gate constants (identical across the 4 lanes of a quad)
    const float wih_r = Wih[u], wih_z = Wih[u + 128], wih_n = Wih[u + 256];
    const float bb_r = bih[u]       + bhh[u];
    const float bb_z = bih[u + 128] + bhh[u + 128];
    const float bi_n = bih[u + 256];
    const float bh_n = bhh[u + 256];
    const float bfc0 = bfc[0];
    float h_old = 0.0f;

    const int rb = kc * 40;                 // f16 chunk base (80 B stride)
    const int pu = u + (u >> 5) * 8;        // padded f16 write index

    __syncthreads();

#pragma unroll 1
    for (int t = 0; t < Tlen; ++t) {
        const __fp16* hb = hbuf[t & 1];
        __fp16*       hw = hbuf[(t + 1) & 1];
        float xt = x_s[t];

        // h chunk: 4x ds_read_b128 (32 packed f16 values)
        const float4* hp = (const float4*)(hb + rb);
        float4 qa = hp[0], qb = hp[1], qc = hp[2], qd = hp[3];
        hf2 h0  = bch(qa.x), h1  = bch(qa.y), h2  = bch(qa.z), h3  = bch(qa.w),
            h4  = bch(qb.x), h5  = bch(qb.y), h6  = bch(qb.z), h7  = bch(qb.w),
            h8  = bch(qc.x), h9  = bch(qc.y), h10 = bch(qc.z), h11 = bch(qc.w),
            h12 = bch(qd.x), h13 = bch(qd.y), h14 = bch(qd.z), h15 = bch(qd.w);

        float ar = 0.f, az = 0.f, an = 0.f, axp = 0.f;
        DOT8L(axp, fl); DOT8H(axp, fh);     // xp first: xh feeds the chain
        DOT8L(ar,  rl); DOT8H(ar,  rh);
        DOT8L(az,  zl); DOT8H(az,  zh);
        DOT8L(an,  nl); DOT8H(an,  nh);

        // 4-lane quad allreduce; every lane of the quad holds the full sums
        float xp = red4(axp);
        float gr = red4(ar);
        float gz = red4(az);
        float gn = red4(an);

        float xh  = xp + bfc0;
        float cur = ((xt == 128.0f) && (t != 0)) ? xh : xt;

        float r  = sigmoidf_(wih_r * cur + bb_r + gr);
        float z  = sigmoidf_(wih_z * cur + bb_z + gz);
        float n  = tanhf_(wih_n * cur + bi_n + r * (gn + bh_n));
        float hn = (1.0f - z) * n + z * h_old;
        h_old = hn;

        if (kc == 0) hw[pu] = (__fp16)hn;   // ds_write_b16, 2-way dword alias = free
        if (tid == 0) {
            x_s[t]  = cur;                  // LDS staging (R14-verified)
            xh_s[t] = xh;
        }
        __syncthreads();
    }

    // bulk flush: one vmcnt drain total instead of one per step
    for (int i = tid; i < Tlen; i += 512)
        out_newin[i * Bsz + b] = x_s[i];
    for (int i = tid; i < Tlen - 1; i += 512)
        out_pred[b * (Tlen - 1) + i] = xh_s[i + 1];
}

extern "C" void kernel_launch(void* const* d_in, const int* in_sizes, int n_in,
                              void* d_out, int out_size, void* d_ws, size_t ws_size,
                              hipStream_t stream) {
    const float* x   = (const float*)d_in[0];
    const float* Wih = (const float*)d_in[1];
    const float* Whh = (const float*)d_in[2];
    const float* bih = (const float*)d_in[3];
    const float* bhh = (const float*)d_in[4];
    const float* Wfc = (const float*)d_in[5];
    const float* bfc = (const float*)d_in[6];

    float* out_newin = (float*)d_out;                 // [T*B] = 524288
    float* out_pred  = out_newin + Tlen * Bsz;        // [B*(T-1)] = 524032

    rnn_imp_kernel<<<Bsz, 512, 0, stream>>>(x, Wih, Whh, bih, bhh, Wfc, bfc,
                                            out_newin, out_pred);
}